// Round 11
// baseline (219.814 us; speedup 1.0000x reference)
//
#include <hip/hip_runtime.h>
#include <hip/hip_bf16.h>

// B=4, L=S=1024, D=1024, H=16, HD=64. History: R16 256^2/BK=64 8-wave GEMM
// core -> 220.7us. R17 attn QBLK=128: 216.2. R18 T2-involution P: conflicts
// ->0. R19 swapped QK^T (S^T=mfma(K,Q), P = 8 ds_write_b64): 210.2 (best).
// R20 proj 256-block regrid (V at NT=128): 217.4 REGRESSION — V per-tile
// barrier overhead doubled + Wv re-read 2x; idle CUs were cheaper. R21:
// (1) proj reverted to R19's 192-block all-256^2 mapping; (2) attn QBLK=64
// (g-dim removed): grid (64,16)=1024 blocks, LDS 40KB -> 4 blocks/CU
// (was 2) — both pipes <30% so doubled TLP should lift them; per-tile
// chain halves. All R18/R19 P-store/swizzle machinery kept (per-wave 1024
// region, same c/phys math, g=0 only).

typedef __bf16 bf16;
typedef __bf16 bf16x4 __attribute__((ext_vector_type(4)));
typedef __bf16 bf16x8 __attribute__((ext_vector_type(8)));
typedef float floatx4 __attribute__((ext_vector_type(4)));

#define D_MODEL 1024
#define NHEAD   16
#define HDIM    64
#define BATCH   4
#define SEQ     1024
#define M_ROWS  (BATCH * SEQ)         // 4096
#define ACT_N   ((size_t)M_ROWS * D_MODEL)    // 4M
#define W_N     ((size_t)D_MODEL * D_MODEL)   // 1M
#define SC2     0.18033688011112042f  // 0.125 * log2(e)

#define GLD(gp, lp) __builtin_amdgcn_global_load_lds( \
    (__attribute__((address_space(1))) void*)(gp), \
    (__attribute__((address_space(3))) void*)(lp), 16, 0, 0)

// ---------------------------------------------------------------------------
// Fused convert + mask (R10-verbatim, verified).
// ---------------------------------------------------------------------------
__global__ __launch_bounds__(256)
void k_convert_all(const float* __restrict__ a0, const float* __restrict__ a1,
                   const float* __restrict__ a2,
                   const float* __restrict__ w0, const float* __restrict__ w1,
                   const float* __restrict__ w2, const float* __restrict__ w3,
                   bf16* __restrict__ dst,
                   const unsigned* __restrict__ m, float* __restrict__ mbias)
{
    if (blockIdx.x == 8192) {
        __shared__ unsigned viol[4];
        __shared__ int fmsh;
        if (threadIdx.x < 4) viol[threadIdx.x] = 0;
        __syncthreads();
        unsigned a = 0, b = 0, c = 0, d = 0;
        for (int i = threadIdx.x; i < 1024; i += 256) {
            unsigned v = m[i];
            if (v > 1u) a = 1;
            if (((v & 0xFFu) > 1u) || (((v >> 8) & 0xFFu) > 1u) ||
                (((v >> 16) & 0xFFu) > 1u) || (((v >> 24) & 0xFFu) > 1u)) b = 1;
            unsigned lo = v & 0xFFFFu, hi = v >> 16;
            if (!((lo == 0u || lo == 0x3F80u) && (hi == 0u || hi == 0x3F80u))) c = 1;
            if (lo != 0u) d = 1;
        }
        if (a) atomicOr(&viol[0], 1u);
        if (b) atomicOr(&viol[1], 1u);
        if (c) atomicOr(&viol[2], 1u);
        if (d) atomicOr(&viol[3], 1u);
        __syncthreads();
        if (threadIdx.x == 0) {
            int fm;
            if (!viol[0])      fm = 1;
            else if (!viol[1]) fm = 0;
            else if (!viol[2]) fm = viol[3] ? 2 : 3;
            else               fm = 0;
            fmsh = fm;
        }
        __syncthreads();
        const int fm = fmsh;
        for (int i = 0; i < 16; ++i) {
            int s = i * 256 + threadIdx.x;
            bool msk;
            if (fm == 1)      msk = ((const int*)m)[s] != 0;
            else if (fm == 2) msk = ((const unsigned short*)m)[s] != 0;
            else if (fm == 3) msk = ((const unsigned*)m)[s] != 0;
            else              msk = ((const unsigned char*)m)[s] != 0;
            mbias[s] = msk ? -1e30f : 0.f;
        }
        return;
    }

    size_t i = ((size_t)blockIdx.x * 256 + threadIdx.x) * 8;
    const float* src; size_t off;
    if (i < ((size_t)12 << 20)) {
        int z = (int)(i >> 22);
        src = (z == 0) ? a0 : (z == 1) ? a1 : a2;
        off = i & (((size_t)1 << 22) - 1);
    } else {
        size_t r = i - ((size_t)12 << 20);
        int j = (int)(r >> 20);
        src = (j == 0) ? w0 : (j == 1) ? w1 : (j == 2) ? w2 : w3;
        off = r & (((size_t)1 << 20) - 1);
    }
    float4 f0 = ((const float4*)(src + off))[0];
    float4 f1 = ((const float4*)(src + off))[1];
    bf16x8 o;
    o[0] = (bf16)f0.x; o[1] = (bf16)f0.y; o[2] = (bf16)f0.z; o[3] = (bf16)f0.w;
    o[4] = (bf16)f1.x; o[5] = (bf16)f1.y; o[6] = (bf16)f1.z; o[7] = (bf16)f1.w;
    *(bf16x8*)(dst + i) = o;
}

// ---------------------------------------------------------------------------
// 256xNT / BK=64 / 8-wave GEMM core (R16-verified at NT=256, R17 at NT=128).
// ---------------------------------------------------------------------------
template<typename CT, int NT>
__device__ __forceinline__ void gemm8_core(const bf16* __restrict__ A,
                                           const bf16* __restrict__ W,
                                           const float* __restrict__ bias,
                                           CT* __restrict__ C,
                                           int m0, int n0, bool rowBias,
                                           bf16* __restrict__ As0,
                                           bf16* __restrict__ Bs0)
{
    const int t    = threadIdx.x;     // 0..511
    const int lane = t & 63;
    const int w    = t >> 6;          // 0..7
    const int wm   = w >> 2;          // 0..1
    const int wn   = w & 3;           // 0..3
    const int l15  = lane & 15;
    const int quad = lane >> 4;
    const int lx   = l15 & 7;

    constexpr int NJ = NT / 128;      // B jj-count per quadrant (2 or 1)
    constexpr int BSTRIDE = NT * 64;  // elems per B buffer

    floatx4 acc[8][NT / 64] = {};

    int srow[2], schk[2], ldso[2];
    #pragma unroll
    for (int j = 0; j < 2; ++j) {
        int i = j * 512 + t;
        srow[j] = i >> 3;
        schk[j] = (i & 7) ^ (srow[j] & 7);
        ldso[j] = (j * 512 + w * 64) * 8;
    }

    #define STAGE_HALF(src, rb, k0s, h, dstbuf) do {                          \
        _Pragma("unroll")                                                     \
        for (int j = 0; j < 2; ++j)                                           \
            GLD((src) + (size_t)((rb) + (h) * 128 + srow[j]) * D_MODEL        \
                    + (k0s) + schk[j] * 8,                                    \
                (dstbuf) + (h) * 8192 + ldso[j]);                             \
    } while (0)

    // prologue: tile 0 -> buffer 0
    STAGE_HALF(A, m0, 0, 0, As0);
    STAGE_HALF(A, m0, 0, 1, As0);
    STAGE_HALF(W, n0, 0, 0, Bs0);
    if constexpr (NT == 256) STAGE_HALF(W, n0, 0, 1, Bs0);
    __syncthreads();

    for (int kt = 0; kt < 16; ++kt) {
        const int nk = (kt + 1) * 64;
        const bf16* __restrict__ Ab = As0 + (kt & 1) * 16384;
        const bf16* __restrict__ Bb = Bs0 + (kt & 1) * BSTRIDE;
        bf16* __restrict__ An = As0 + ((kt + 1) & 1) * 16384;
        bf16* __restrict__ Bn = Bs0 + ((kt + 1) & 1) * BSTRIDE;

        #pragma unroll
        for (int ph = 0; ph < 4; ++ph) {
            const int mq = ph >> 1, nq = ph & 1;

            if (nk < D_MODEL) {       // stage one half of tile kt+1
                if constexpr (NT == 256) {
                    if (ph == 0)      STAGE_HALF(A, m0, nk, 0, An);
                    else if (ph == 1) STAGE_HALF(A, m0, nk, 1, An);
                    else if (ph == 2) STAGE_HALF(W, n0, nk, 0, Bn);
                    else              STAGE_HALF(W, n0, nk, 1, Bn);
                } else {
                    if (ph == 0)      STAGE_HALF(A, m0, nk, 0, An);
                    else if (ph == 1) STAGE_HALF(A, m0, nk, 1, An);
                    else if (ph == 2) STAGE_HALF(W, n0, nk, 0, Bn);
                }
            }

            bf16x8 af[4][2], bfr[NJ][2];
            #pragma unroll
            for (int ii = 0; ii < 4; ++ii) {
                int row = wm * 128 + mq * 64 + ii * 16 + l15;
                #pragma unroll
                for (int kk = 0; kk < 2; ++kk)
                    af[ii][kk] = *(const bf16x8*)
                        &Ab[row * 64 + (((kk * 4 + quad) ^ lx)) * 8];
            }
            #pragma unroll
            for (int jj = 0; jj < NJ; ++jj) {
                int row = wn * (NT / 4) + nq * (NT / 8) + jj * 16 + l15;
                #pragma unroll
                for (int kk = 0; kk < 2; ++kk)
                    bfr[jj][kk] = *(const bf16x8*)
                        &Bb[row * 64 + (((kk * 4 + quad) ^ lx)) * 8];
            }

            #pragma unroll
            for (int ii = 0; ii < 4; ++ii)
                #pragma unroll
                for (int jj = 0; jj < NJ; ++jj)
                    #pragma unroll
                    for (int kk = 0; kk < 2; ++kk)
                        acc[mq * 4 + ii][nq * NJ + jj] =
                            __builtin_amdgcn_mfma_f32_16x16x32_bf16(
                                af[ii][kk], bfr[jj][kk],
                                acc[mq * 4 + ii][nq * NJ + jj], 0, 0, 0);
        }
        __syncthreads();
    }

    // epilogue: C/D layout col=lane&15, row=quad*4+r
    #pragma unroll
    for (int i = 0; i < 8; ++i) {
        int rowb = m0 + wm * 128 + i * 16 + quad * 4;
        float bvr[4];
        if (rowBias) {
            #pragma unroll
            for (int r = 0; r < 4; ++r) bvr[r] = bias[rowb + r];
        }
        #pragma unroll
        for (int jf = 0; jf < NT / 64; ++jf) {
            int col = n0 + wn * (NT / 4) + jf * 16 + l15;
            float bc = rowBias ? 0.f : bias[col];
            #pragma unroll
            for (int r = 0; r < 4; ++r) {
                float val = acc[i][jf][r] + (rowBias ? bvr[r] : bc);
                C[(size_t)(rowb + r) * D_MODEL + col] = (CT)val;
            }
        }
    }
    #undef STAGE_HALF
}

// ---------------------------------------------------------------------------
// Fused projection GEMM (R19-verified mapping, reverted from R20): 192
// blocks x 512 thr, XCD-chunked tid=(bid&7)*24+(bid>>3). tid<64: Q 256^2;
// <128: K 256^2; else V 256^2 per batch (Vt_b = Wv @ value_b^T + bv by
// row): b=(tid-128)>>4, m=((tid-128)>>2)&3, n=(tid-128)&3.
// ---------------------------------------------------------------------------
__global__ __launch_bounds__(512, 2)
void k_gemm_proj(const bf16* __restrict__ cq, const bf16* __restrict__ ck,
                 const bf16* __restrict__ cv,
                 const bf16* __restrict__ cWq, const bf16* __restrict__ cWk,
                 const bf16* __restrict__ cWv,
                 const float* __restrict__ bq, const float* __restrict__ bk,
                 const float* __restrict__ bv,
                 bf16* __restrict__ qproj, bf16* __restrict__ kproj,
                 bf16* __restrict__ vt)
{
    extern __shared__ __align__(16) bf16 smem[];
    bf16* As0 = smem;            // 2 x 16384 elems
    bf16* Bs0 = smem + 32768;    // 2 x 16384 elems

    const int bid = blockIdx.x;
    const int tid = (bid & 7) * 24 + (bid >> 3);   // 0..191
    if (tid < 64) {
        gemm8_core<bf16, 256>(cq, cWq, bq, qproj,
                              (tid >> 2) * 256, (tid & 3) * 256, false, As0, Bs0);
    } else if (tid < 128) {
        int u = tid - 64;
        gemm8_core<bf16, 256>(ck, cWk, bk, kproj,
                              (u >> 2) * 256, (u & 3) * 256, false, As0, Bs0);
    } else {
        int v = tid - 128;
        int b = v >> 4, m = (v >> 2) & 3, n = v & 3;
        gemm8_core<bf16, 256>(cWv, cv + (size_t)b * W_N, bv,
                              vt + (size_t)b * W_N, m * 256, n * 256, true,
                              As0, Bs0);
    }
}

// O-projection: 128 blocks x 512 thr, 256x128 tiles (16 m x 8 n), XCD-chunked.
__global__ __launch_bounds__(512, 2)
void k_gemm_o(const bf16* __restrict__ A, const bf16* __restrict__ W,
              const float* __restrict__ bb, float* __restrict__ C)
{
    extern __shared__ __align__(16) bf16 smem[];
    bf16* As0 = smem;            // 2 x 16384 elems
    bf16* Bs0 = smem + 32768;    // 2 x 8192 elems

    const int bid = blockIdx.x;
    const int tid = (bid & 7) * 16 + (bid >> 3);   // 0..127
    gemm8_core<float, 128>(A, W, bb, C, (tid >> 3) * 256, (tid & 7) * 128,
                           false, As0, Bs0);
}

// ---------------------------------------------------------------------------
// Flash attention, QBLK=64 (R21), swapped QK^T + T2-involution P (R18/R19
// machinery, g-dim removed). Grid (B*H=64, L/64=16) = 1024 blocks, 256 thr
// (4 waves); wave owns 16 q-rows. LDS: Kst 16K + Vst 16K + Past 8K = 40KB
// -> 4 blocks/CU (grid-limited to 4). Per 64-s tile per wave: QK^T 8 MFMA,
// softmax 16 exp2 + 4 ds_write_b64, accl 2 + PV 8 MFMA.
// ---------------------------------------------------------------------------
__global__ __launch_bounds__(256)
void k_attn(const bf16* __restrict__ qproj, const bf16* __restrict__ kproj,
            const bf16* __restrict__ vt, const float* __restrict__ mbias_g,
            bf16* __restrict__ ctx)
{
    __shared__ alignas(16) bf16 Kst[2][4096];  // [f=j*2+kk][lane]*8, frag order
    __shared__ alignas(16) bf16 Vst[2][4096];
    __shared__ alignas(16) bf16 Past[4096];    // per-wave 1024, swizzled

    const int t    = threadIdx.x;
    const int lane = t & 63;
    const int w    = t >> 6;
    const int l15  = lane & 15;
    const int quad = lane >> 4;

    const int b  = blockIdx.x >> 4;
    const int h  = blockIdx.x & 15;
    const int q0 = blockIdx.y * 64;

    // stage K/V tile 0 into buffer 0
    #pragma unroll
    for (int i = 0; i < 2; ++i) {
        int f   = w * 2 + i;
        int row = (f >> 1) * 16 + l15;          // s-row (K) / d-row (Vt)
        int cb  = (f & 1) * 32 + quad * 8;
        GLD(kproj + (size_t)(b * SEQ + row) * D_MODEL + h * HDIM + cb,
            Kst[0] + f * 512);
        GLD(vt + (size_t)(b * 1024 + h * HDIM + row) * D_MODEL + cb,
            Vst[0] + f * 512);
    }

    // Q fragments: direct per-lane 16B global loads (B-operand layout)
    bf16x8 qf[2];
    #pragma unroll
    for (int kk = 0; kk < 2; ++kk)
        qf[kk] = *(const bf16x8*)(qproj
            + (size_t)(b * SEQ + q0 + w * 16 + l15) * D_MODEL
            + h * HDIM + kk * 32 + quad * 8);

    __syncthreads();

    bf16x8 ones;
    #pragma unroll
    for (int e = 0; e < 8; ++e) ones[e] = (bf16)1.0f;

    floatx4 o[4] = {};
    floatx4 accl = {};

    const int rswz = lane ^ ((lane >> 3) & 7);   // read-side swizzled chunk
    const float* __restrict__ mbb = mbias_g + b * SEQ;

    int cur = 0;
    for (int s0 = 0; s0 < SEQ; s0 += 64) {
        // prefetch next K/V tile into the other buffer BEFORE compute
        if (s0 + 64 < SEQ) {
            #pragma unroll
            for (int i = 0; i < 2; ++i) {
                int f   = w * 2 + i;
                int row = (f >> 1) * 16 + l15;
                int cb  = (f & 1) * 32 + quad * 8;
                GLD(kproj + (size_t)(b * SEQ + s0 + 64 + row) * D_MODEL
                        + h * HDIM + cb,
                    Kst[cur ^ 1] + f * 512);
                GLD(vt + (size_t)(b * 1024 + h * HDIM + row) * D_MODEL
                        + s0 + 64 + cb,
                    Vst[cur ^ 1] + f * 512);
            }
        }

        // swapped QK^T: S^T[s][q] = mfma(A=K, B=Q)
        floatx4 s_acc[4] = {};
        #pragma unroll
        for (int j = 0; j < 4; ++j) {
            bf16x8 kf0 = *(const bf16x8*)&Kst[cur][(j * 2 + 0) * 512 + lane * 8];
            bf16x8 kf1 = *(const bf16x8*)&Kst[cur][(j * 2 + 1) * 512 + lane * 8];
            s_acc[j] = __builtin_amdgcn_mfma_f32_16x16x32_bf16(
                kf0, qf[0], s_acc[j], 0, 0, 0);
            s_acc[j] = __builtin_amdgcn_mfma_f32_16x16x32_bf16(
                kf1, qf[1], s_acc[j], 0, 0, 0);
        }

        // softmax numerator -> packed b64 P store (4 consecutive s per write)
        #pragma unroll
        for (int j = 0; j < 4; ++j) {
            float4 mb4 = *(const float4*)&mbb[s0 + j * 16 + quad * 4];
            int c = (j >> 1) * 64 + ((j & 1) * 2 + (quad >> 1)) * 16 + l15;
            int phys = c ^ ((c >> 3) & 7);
            bf16x4 pk;
            pk[0] = (bf16)__builtin_amdgcn_exp2f(fmaf(s_acc[j][0], SC2, mb4.x));
            pk[1] = (bf16)__builtin_amdgcn_exp2f(fmaf(s_acc[j][1], SC2, mb4.y));
            pk[2] = (bf16)__builtin_amdgcn_exp2f(fmaf(s_acc[j][2], SC2, mb4.z));
            pk[3] = (bf16)__builtin_amdgcn_exp2f(fmaf(s_acc[j][3], SC2, mb4.w));
            *(bf16x4*)&Past[w * 1024 + phys * 8 + (quad & 1) * 4] = pk;
        }
        __builtin_amdgcn_wave_barrier();

        bf16x8 pf[2];
        #pragma unroll
        for (int kk = 0; kk < 2; ++kk)
            pf[kk] = *(const bf16x8*)&Past[w * 1024 + (kk * 64 + rswz) * 8];

        #pragma unroll
        for (int kk = 0; kk < 2; ++kk)
            accl = __builtin_amdgcn_mfma_f32_16x16x32_bf16(pf[kk], ones, accl,
                                                           0, 0, 0);

        #pragma unroll
        for (int j = 0; j < 4; ++j) {
            bf16x8 vf0 = *(const bf16x8*)&Vst[cur][(j * 2 + 0) * 512 + lane * 8];
            bf16x8 vf1 = *(const bf16x8*)&Vst[cur][(j * 2 + 1) * 512 + lane * 8];
            o[j] = __builtin_amdgcn_mfma_f32_16x16x32_bf16(
                pf[0], vf0, o[j], 0, 0, 0);
            o[j] = __builtin_amdgcn_mfma_f32_16x16x32_bf16(
                pf[1], vf1, o[j], 0, 0, 0);
        }

        __syncthreads();   // next K/V tile landed; buffers swap
        cur ^= 1;
    }

    float inv[4];
    #pragma unroll
    for (int r = 0; r < 4; ++r)
        inv[r] = (accl[r] > 0.f) ? 1.f / accl[r] : 0.f;
    #pragma unroll
    for (int j = 0; j < 4; ++j)
        #pragma unroll
        for (int r = 0; r < 4; ++r) {
            int row = q0 + w * 16 + quad * 4 + r;
            int col = h * HDIM + j * 16 + l15;
            ctx[(size_t)(b * SEQ + row) * D_MODEL + col] =
                (bf16)(o[j][r] * inv[r]);
        }
}

// ---------------------------------------------------------------------------
extern "C" void kernel_launch(void* const* d_in, const int* in_sizes, int n_in,
                              void* d_out, int out_size, void* d_ws, size_t ws_size,
                              hipStream_t stream)
{
    // ws: [0,16K) mbias fp32 | [64K,+32MB) converted bf16 (q,k,v,Wq,Wk,Wv,Wo)
    //     | qproj 8MB | kproj 8MB | vt 8MB | ctx 8MB.   Total ~64.1MB.
    char* wsb = (char*)d_ws;
    float* mbias = (float*)wsb;
    bf16* cbase = (bf16*)(wsb + 65536);
    bf16 *cq = cbase, *ck = cq + ACT_N, *cv = ck + ACT_N;
    bf16 *cWq = cv + ACT_N, *cWk = cWq + W_N, *cWv = cWk + W_N, *cWo = cWv + W_N;
    bf16* qproj = cWo + W_N;
    bf16* kproj = qproj + ACT_N;
    bf16* vt    = kproj + ACT_N;
    bf16* ctx   = vt + ACT_N;
    float* out  = (float*)d_out;

    // allow big dynamic LDS on the 8-wave GEMMs (host-side, capture-safe)
    static bool attrset = false;
    if (!attrset) {
        hipFuncSetAttribute((const void*)k_gemm_proj,
                            hipFuncAttributeMaxDynamicSharedMemorySize, 131072);
        hipFuncSetAttribute((const void*)k_gemm_o,
                            hipFuncAttributeMaxDynamicSharedMemorySize, 131072);
        attrset = true;
    }

    k_convert_all<<<8193, 256, 0, stream>>>(
        (const float*)d_in[0], (const float*)d_in[1], (const float*)d_in[2],
        (const float*)d_in[4], (const float*)d_in[6], (const float*)d_in[8],
        (const float*)d_in[10], cbase, (const unsigned*)d_in[3], mbias);

    k_gemm_proj<<<192, 512, 131072, stream>>>(cq, ck, cv, cWq, cWk, cWv,
                                              (const float*)d_in[5],
                                              (const float*)d_in[7],
                                              (const float*)d_in[9],
                                              qproj, kproj, vt);
    k_attn<<<dim3(64, 16), 256, 0, stream>>>(qproj, kproj, vt, mbias, ctx);
    k_gemm_o<<<128, 512, 98304, stream>>>(ctx, cWo, (const float*)d_in[11], out);
}

// Round 12
// 214.691 us; speedup vs baseline: 1.0239x; 1.0239x over previous
//
#include <hip/hip_runtime.h>
#include <hip/hip_bf16.h>

// B=4, L=S=1024, D=1024, H=16, HD=64. History: R16 256^2/BK=64 8-wave GEMMs.
// R19 (best, 210.2us): proj 192-blk all-256^2; attn QBLK=128 swapped-QK^T
// (S^T=mfma(K,Q)), T2-involution P both sides, Q in regs. R20 V-NT=128
// regrid: 217 ✗. R21 QBLK=64 (2x TLP): 220 ✗ — lesson x3: work-per-barrier
// dominates, TLP>2blk/CU buys nothing. R22: attn back to QBLK=128 + T15
// double-pipeline: iteration t runs QK^T(t) ∥ PV(t-1) (pf_prev+vfp in regs)
// so softmax(t) VALU overlaps PV(t-1) MFMA. V triple-buffered (V(t-1) read
// vs V(t+1) GLD — disjoint bufs, no GLD-timing assumption); K 2-buf (K(t-1)
// never read); Past single (per-wave, DS wave-ordered). 1 syncthreads/tile
// unchanged. LDS 56KB -> 2 blk/CU. proj/o-proj/convert = R19 verbatim.

typedef __bf16 bf16;
typedef __bf16 bf16x4 __attribute__((ext_vector_type(4)));
typedef __bf16 bf16x8 __attribute__((ext_vector_type(8)));
typedef float floatx4 __attribute__((ext_vector_type(4)));

#define D_MODEL 1024
#define NHEAD   16
#define HDIM    64
#define BATCH   4
#define SEQ     1024
#define M_ROWS  (BATCH * SEQ)         // 4096
#define ACT_N   ((size_t)M_ROWS * D_MODEL)    // 4M
#define W_N     ((size_t)D_MODEL * D_MODEL)   // 1M
#define SC2     0.18033688011112042f  // 0.125 * log2(e)

#define GLD(gp, lp) __builtin_amdgcn_global_load_lds( \
    (__attribute__((address_space(1))) void*)(gp), \
    (__attribute__((address_space(3))) void*)(lp), 16, 0, 0)

// ---------------------------------------------------------------------------
// Fused convert + mask (R10-verbatim, verified).
// ---------------------------------------------------------------------------
__global__ __launch_bounds__(256)
void k_convert_all(const float* __restrict__ a0, const float* __restrict__ a1,
                   const float* __restrict__ a2,
                   const float* __restrict__ w0, const float* __restrict__ w1,
                   const float* __restrict__ w2, const float* __restrict__ w3,
                   bf16* __restrict__ dst,
                   const unsigned* __restrict__ m, float* __restrict__ mbias)
{
    if (blockIdx.x == 8192) {
        __shared__ unsigned viol[4];
        __shared__ int fmsh;
        if (threadIdx.x < 4) viol[threadIdx.x] = 0;
        __syncthreads();
        unsigned a = 0, b = 0, c = 0, d = 0;
        for (int i = threadIdx.x; i < 1024; i += 256) {
            unsigned v = m[i];
            if (v > 1u) a = 1;
            if (((v & 0xFFu) > 1u) || (((v >> 8) & 0xFFu) > 1u) ||
                (((v >> 16) & 0xFFu) > 1u) || (((v >> 24) & 0xFFu) > 1u)) b = 1;
            unsigned lo = v & 0xFFFFu, hi = v >> 16;
            if (!((lo == 0u || lo == 0x3F80u) && (hi == 0u || hi == 0x3F80u))) c = 1;
            if (lo != 0u) d = 1;
        }
        if (a) atomicOr(&viol[0], 1u);
        if (b) atomicOr(&viol[1], 1u);
        if (c) atomicOr(&viol[2], 1u);
        if (d) atomicOr(&viol[3], 1u);
        __syncthreads();
        if (threadIdx.x == 0) {
            int fm;
            if (!viol[0])      fm = 1;
            else if (!viol[1]) fm = 0;
            else if (!viol[2]) fm = viol[3] ? 2 : 3;
            else               fm = 0;
            fmsh = fm;
        }
        __syncthreads();
        const int fm = fmsh;
        for (int i = 0; i < 16; ++i) {
            int s = i * 256 + threadIdx.x;
            bool msk;
            if (fm == 1)      msk = ((const int*)m)[s] != 0;
            else if (fm == 2) msk = ((const unsigned short*)m)[s] != 0;
            else if (fm == 3) msk = ((const unsigned*)m)[s] != 0;
            else              msk = ((const unsigned char*)m)[s] != 0;
            mbias[s] = msk ? -1e30f : 0.f;
        }
        return;
    }

    size_t i = ((size_t)blockIdx.x * 256 + threadIdx.x) * 8;
    const float* src; size_t off;
    if (i < ((size_t)12 << 20)) {
        int z = (int)(i >> 22);
        src = (z == 0) ? a0 : (z == 1) ? a1 : a2;
        off = i & (((size_t)1 << 22) - 1);
    } else {
        size_t r = i - ((size_t)12 << 20);
        int j = (int)(r >> 20);
        src = (j == 0) ? w0 : (j == 1) ? w1 : (j == 2) ? w2 : w3;
        off = r & (((size_t)1 << 20) - 1);
    }
    float4 f0 = ((const float4*)(src + off))[0];
    float4 f1 = ((const float4*)(src + off))[1];
    bf16x8 o;
    o[0] = (bf16)f0.x; o[1] = (bf16)f0.y; o[2] = (bf16)f0.z; o[3] = (bf16)f0.w;
    o[4] = (bf16)f1.x; o[5] = (bf16)f1.y; o[6] = (bf16)f1.z; o[7] = (bf16)f1.w;
    *(bf16x8*)(dst + i) = o;
}

// ---------------------------------------------------------------------------
// 256xNT / BK=64 / 8-wave GEMM core (R16-verified at NT=256, R17 at NT=128).
// ---------------------------------------------------------------------------
template<typename CT, int NT>
__device__ __forceinline__ void gemm8_core(const bf16* __restrict__ A,
                                           const bf16* __restrict__ W,
                                           const float* __restrict__ bias,
                                           CT* __restrict__ C,
                                           int m0, int n0, bool rowBias,
                                           bf16* __restrict__ As0,
                                           bf16* __restrict__ Bs0)
{
    const int t    = threadIdx.x;     // 0..511
    const int lane = t & 63;
    const int w    = t >> 6;          // 0..7
    const int wm   = w >> 2;          // 0..1
    const int wn   = w & 3;           // 0..3
    const int l15  = lane & 15;
    const int quad = lane >> 4;
    const int lx   = l15 & 7;

    constexpr int NJ = NT / 128;      // B jj-count per quadrant (2 or 1)
    constexpr int BSTRIDE = NT * 64;  // elems per B buffer

    floatx4 acc[8][NT / 64] = {};

    int srow[2], schk[2], ldso[2];
    #pragma unroll
    for (int j = 0; j < 2; ++j) {
        int i = j * 512 + t;
        srow[j] = i >> 3;
        schk[j] = (i & 7) ^ (srow[j] & 7);
        ldso[j] = (j * 512 + w * 64) * 8;
    }

    #define STAGE_HALF(src, rb, k0s, h, dstbuf) do {                          \
        _Pragma("unroll")                                                     \
        for (int j = 0; j < 2; ++j)                                           \
            GLD((src) + (size_t)((rb) + (h) * 128 + srow[j]) * D_MODEL        \
                    + (k0s) + schk[j] * 8,                                    \
                (dstbuf) + (h) * 8192 + ldso[j]);                             \
    } while (0)

    // prologue: tile 0 -> buffer 0
    STAGE_HALF(A, m0, 0, 0, As0);
    STAGE_HALF(A, m0, 0, 1, As0);
    STAGE_HALF(W, n0, 0, 0, Bs0);
    if constexpr (NT == 256) STAGE_HALF(W, n0, 0, 1, Bs0);
    __syncthreads();

    for (int kt = 0; kt < 16; ++kt) {
        const int nk = (kt + 1) * 64;
        const bf16* __restrict__ Ab = As0 + (kt & 1) * 16384;
        const bf16* __restrict__ Bb = Bs0 + (kt & 1) * BSTRIDE;
        bf16* __restrict__ An = As0 + ((kt + 1) & 1) * 16384;
        bf16* __restrict__ Bn = Bs0 + ((kt + 1) & 1) * BSTRIDE;

        #pragma unroll
        for (int ph = 0; ph < 4; ++ph) {
            const int mq = ph >> 1, nq = ph & 1;

            if (nk < D_MODEL) {       // stage one half of tile kt+1
                if constexpr (NT == 256) {
                    if (ph == 0)      STAGE_HALF(A, m0, nk, 0, An);
                    else if (ph == 1) STAGE_HALF(A, m0, nk, 1, An);
                    else if (ph == 2) STAGE_HALF(W, n0, nk, 0, Bn);
                    else              STAGE_HALF(W, n0, nk, 1, Bn);
                } else {
                    if (ph == 0)      STAGE_HALF(A, m0, nk, 0, An);
                    else if (ph == 1) STAGE_HALF(A, m0, nk, 1, An);
                    else if (ph == 2) STAGE_HALF(W, n0, nk, 0, Bn);
                }
            }

            bf16x8 af[4][2], bfr[NJ][2];
            #pragma unroll
            for (int ii = 0; ii < 4; ++ii) {
                int row = wm * 128 + mq * 64 + ii * 16 + l15;
                #pragma unroll
                for (int kk = 0; kk < 2; ++kk)
                    af[ii][kk] = *(const bf16x8*)
                        &Ab[row * 64 + (((kk * 4 + quad) ^ lx)) * 8];
            }
            #pragma unroll
            for (int jj = 0; jj < NJ; ++jj) {
                int row = wn * (NT / 4) + nq * (NT / 8) + jj * 16 + l15;
                #pragma unroll
                for (int kk = 0; kk < 2; ++kk)
                    bfr[jj][kk] = *(const bf16x8*)
                        &Bb[row * 64 + (((kk * 4 + quad) ^ lx)) * 8];
            }

            #pragma unroll
            for (int ii = 0; ii < 4; ++ii)
                #pragma unroll
                for (int jj = 0; jj < NJ; ++jj)
                    #pragma unroll
                    for (int kk = 0; kk < 2; ++kk)
                        acc[mq * 4 + ii][nq * NJ + jj] =
                            __builtin_amdgcn_mfma_f32_16x16x32_bf16(
                                af[ii][kk], bfr[jj][kk],
                                acc[mq * 4 + ii][nq * NJ + jj], 0, 0, 0);
        }
        __syncthreads();
    }

    // epilogue: C/D layout col=lane&15, row=quad*4+r
    #pragma unroll
    for (int i = 0; i < 8; ++i) {
        int rowb = m0 + wm * 128 + i * 16 + quad * 4;
        float bvr[4];
        if (rowBias) {
            #pragma unroll
            for (int r = 0; r < 4; ++r) bvr[r] = bias[rowb + r];
        }
        #pragma unroll
        for (int jf = 0; jf < NT / 64; ++jf) {
            int col = n0 + wn * (NT / 4) + jf * 16 + l15;
            float bc = rowBias ? 0.f : bias[col];
            #pragma unroll
            for (int r = 0; r < 4; ++r) {
                float val = acc[i][jf][r] + (rowBias ? bvr[r] : bc);
                C[(size_t)(rowb + r) * D_MODEL + col] = (CT)val;
            }
        }
    }
    #undef STAGE_HALF
}

// ---------------------------------------------------------------------------
// Fused projection GEMM (R19-verified): 192 blocks x 512 thr, XCD-chunked.
// ---------------------------------------------------------------------------
__global__ __launch_bounds__(512, 2)
void k_gemm_proj(const bf16* __restrict__ cq, const bf16* __restrict__ ck,
                 const bf16* __restrict__ cv,
                 const bf16* __restrict__ cWq, const bf16* __restrict__ cWk,
                 const bf16* __restrict__ cWv,
                 const float* __restrict__ bq, const float* __restrict__ bk,
                 const float* __restrict__ bv,
                 bf16* __restrict__ qproj, bf16* __restrict__ kproj,
                 bf16* __restrict__ vt)
{
    extern __shared__ __align__(16) bf16 smem[];
    bf16* As0 = smem;            // 2 x 16384 elems
    bf16* Bs0 = smem + 32768;    // 2 x 16384 elems

    const int bid = blockIdx.x;
    const int tid = (bid & 7) * 24 + (bid >> 3);   // 0..191
    if (tid < 64) {
        gemm8_core<bf16, 256>(cq, cWq, bq, qproj,
                              (tid >> 2) * 256, (tid & 3) * 256, false, As0, Bs0);
    } else if (tid < 128) {
        int u = tid - 64;
        gemm8_core<bf16, 256>(ck, cWk, bk, kproj,
                              (u >> 2) * 256, (u & 3) * 256, false, As0, Bs0);
    } else {
        int v = tid - 128;
        int b = v >> 4, m = (v >> 2) & 3, n = v & 3;
        gemm8_core<bf16, 256>(cWv, cv + (size_t)b * W_N, bv,
                              vt + (size_t)b * W_N, m * 256, n * 256, true,
                              As0, Bs0);
    }
}

// O-projection: 128 blocks x 512 thr, 256x128 tiles (16 m x 8 n), XCD-chunked.
__global__ __launch_bounds__(512, 2)
void k_gemm_o(const bf16* __restrict__ A, const bf16* __restrict__ W,
              const float* __restrict__ bb, float* __restrict__ C)
{
    extern __shared__ __align__(16) bf16 smem[];
    bf16* As0 = smem;            // 2 x 16384 elems
    bf16* Bs0 = smem + 32768;    // 2 x 8192 elems

    const int bid = blockIdx.x;
    const int tid = (bid & 7) * 16 + (bid >> 3);   // 0..127
    gemm8_core<float, 128>(A, W, bb, C, (tid >> 3) * 256, (tid & 7) * 128,
                           false, As0, Bs0);
}

// ---------------------------------------------------------------------------
// Flash attention, QBLK=128, swapped QK^T, T15 double-pipeline (R22).
// Grid (64, 8) = 512 blocks, 256 thr (4 waves); wave owns 32 q = 2 groups.
// Iteration t: prefetch K/V(t+1); read vfp=V(t-1) regs; QK^T(t) MFMA;
// PV(t-1) MFMA (pf_prev regs) ∥ softmax(t) VALU; P-write(t); wave_barrier;
// pf_prev=read P(t); syncthreads. V 3-buffered (read t-1 vs GLD t+1 =
// disjoint); K 2-buffered; Past single per-wave. Epilogue: PV(15).
// LDS: Kst 16K + Vst 24K + Past 16K = 56KB -> 2 blocks/CU.
// ---------------------------------------------------------------------------
__global__ __launch_bounds__(256)
void k_attn(const bf16* __restrict__ qproj, const bf16* __restrict__ kproj,
            const bf16* __restrict__ vt, const float* __restrict__ mbias_g,
            bf16* __restrict__ ctx)
{
    __shared__ alignas(16) bf16 Kst[2][4096];  // [f=j*2+kk][lane]*8, frag order
    __shared__ alignas(16) bf16 Vst[3][4096];  // triple-buffered
    __shared__ alignas(16) bf16 Past[8192];    // per-wave 2048, swizzled

    const int t    = threadIdx.x;
    const int lane = t & 63;
    const int w    = t >> 6;
    const int l15  = lane & 15;
    const int quad = lane >> 4;

    const int b  = blockIdx.x >> 4;
    const int h  = blockIdx.x & 15;
    const int q0 = blockIdx.y * 128;

    #define STAGE_KV(s0s, kbuf, vbuf) do {                                    \
        _Pragma("unroll")                                                     \
        for (int i = 0; i < 2; ++i) {                                         \
            int f   = w * 2 + i;                                              \
            int row = (f >> 1) * 16 + l15;                                    \
            int cb  = (f & 1) * 32 + quad * 8;                                \
            GLD(kproj + (size_t)(b * SEQ + (s0s) + row) * D_MODEL             \
                    + h * HDIM + cb,                                          \
                Kst[kbuf] + f * 512);                                         \
            GLD(vt + (size_t)(b * 1024 + h * HDIM + row) * D_MODEL            \
                    + (s0s) + cb,                                             \
                Vst[vbuf] + f * 512);                                         \
        }                                                                     \
    } while (0)

    // stage K/V tile 0
    STAGE_KV(0, 0, 0);

    // Q fragments: direct per-lane 16B global loads (B-operand layout)
    bf16x8 qf[2][2];
    #pragma unroll
    for (int g = 0; g < 2; ++g)
        #pragma unroll
        for (int kk = 0; kk < 2; ++kk)
            qf[g][kk] = *(const bf16x8*)(qproj
                + (size_t)(b * SEQ + q0 + w * 32 + g * 16 + l15) * D_MODEL
                + h * HDIM + kk * 32 + quad * 8);

    __syncthreads();

    bf16x8 ones;
    #pragma unroll
    for (int e = 0; e < 8; ++e) ones[e] = (bf16)1.0f;

    floatx4 o[2][4] = {};
    floatx4 accl[2] = {};
    bf16x8 pf_prev[2][2];

    const int rswz = lane ^ ((lane >> 3) & 7);   // read-side swizzled chunk
    const float* __restrict__ mbb = mbias_g + b * SEQ;

    int cur = 0;
    int vbp = 2, vb = 0, vbn = 1;   // entering t: vb == t%3

    for (int ti = 0; ti < 16; ++ti) {
        const int s0 = ti * 64;
        if (ti < 15)
            STAGE_KV(s0 + 64, cur ^ 1, vbn);

        // V(t-1) fragments to regs (buffer vbp — disjoint from vbn prefetch)
        bf16x8 vfp[4][2];
        if (ti > 0) {
            #pragma unroll
            for (int j = 0; j < 4; ++j)
                #pragma unroll
                for (int kk = 0; kk < 2; ++kk)
                    vfp[j][kk] = *(const bf16x8*)
                        &Vst[vbp][(j * 2 + kk) * 512 + lane * 8];
        }

        // QK^T(t): S^T[s][q] = mfma(A=K, B=Q)
        floatx4 s_acc[2][4] = {};
        #pragma unroll
        for (int j = 0; j < 4; ++j) {
            bf16x8 kf0 = *(const bf16x8*)&Kst[cur][(j * 2 + 0) * 512 + lane * 8];
            bf16x8 kf1 = *(const bf16x8*)&Kst[cur][(j * 2 + 1) * 512 + lane * 8];
            #pragma unroll
            for (int g = 0; g < 2; ++g) {
                s_acc[g][j] = __builtin_amdgcn_mfma_f32_16x16x32_bf16(
                    kf0, qf[g][0], s_acc[g][j], 0, 0, 0);
                s_acc[g][j] = __builtin_amdgcn_mfma_f32_16x16x32_bf16(
                    kf1, qf[g][1], s_acc[g][j], 0, 0, 0);
            }
        }

        // PV(t-1) — MFMA pipe; overlaps softmax(t) VALU below
        if (ti > 0) {
            #pragma unroll
            for (int g = 0; g < 2; ++g)
                #pragma unroll
                for (int kk = 0; kk < 2; ++kk)
                    accl[g] = __builtin_amdgcn_mfma_f32_16x16x32_bf16(
                        pf_prev[g][kk], ones, accl[g], 0, 0, 0);
            #pragma unroll
            for (int j = 0; j < 4; ++j)
                #pragma unroll
                for (int g = 0; g < 2; ++g) {
                    o[g][j] = __builtin_amdgcn_mfma_f32_16x16x32_bf16(
                        pf_prev[g][0], vfp[j][0], o[g][j], 0, 0, 0);
                    o[g][j] = __builtin_amdgcn_mfma_f32_16x16x32_bf16(
                        pf_prev[g][1], vfp[j][1], o[g][j], 0, 0, 0);
                }
        }

        // softmax(t) -> packed b64 P store (T2 involution, R18/R19-verified)
        #pragma unroll
        for (int j = 0; j < 4; ++j) {
            float4 mb4 = *(const float4*)&mbb[s0 + j * 16 + quad * 4];
            int c = (j >> 1) * 64 + ((j & 1) * 2 + (quad >> 1)) * 16 + l15;
            int phys = c ^ ((c >> 3) & 7);
            #pragma unroll
            for (int g = 0; g < 2; ++g) {
                bf16x4 pk;
                pk[0] = (bf16)__builtin_amdgcn_exp2f(
                    fmaf(s_acc[g][j][0], SC2, mb4.x));
                pk[1] = (bf16)__builtin_amdgcn_exp2f(
                    fmaf(s_acc[g][j][1], SC2, mb4.y));
                pk[2] = (bf16)__builtin_amdgcn_exp2f(
                    fmaf(s_acc[g][j][2], SC2, mb4.z));
                pk[3] = (bf16)__builtin_amdgcn_exp2f(
                    fmaf(s_acc[g][j][3], SC2, mb4.w));
                *(bf16x4*)&Past[(w * 2 + g) * 1024 + phys * 8
                                + (quad & 1) * 4] = pk;
            }
        }
        __builtin_amdgcn_wave_barrier();

        #pragma unroll
        for (int g = 0; g < 2; ++g)
            #pragma unroll
            for (int kk = 0; kk < 2; ++kk)
                pf_prev[g][kk] = *(const bf16x8*)
                    &Past[(w * 2 + g) * 1024 + (kk * 64 + rswz) * 8];

        __syncthreads();   // tile t+1 landed; P(t) consumed into regs
        cur ^= 1;
        int tmp = vbp; vbp = vb; vb = vbn; vbn = tmp;
    }

    // epilogue: PV(15) — V(15) in Vst[vbp] (staged at t=14 into (15)%3)
    {
        bf16x8 vfp[4][2];
        #pragma unroll
        for (int j = 0; j < 4; ++j)
            #pragma unroll
            for (int kk = 0; kk < 2; ++kk)
                vfp[j][kk] = *(const bf16x8*)
                    &Vst[vbp][(j * 2 + kk) * 512 + lane * 8];
        #pragma unroll
        for (int g = 0; g < 2; ++g)
            #pragma unroll
            for (int kk = 0; kk < 2; ++kk)
                accl[g] = __builtin_amdgcn_mfma_f32_16x16x32_bf16(
                    pf_prev[g][kk], ones, accl[g], 0, 0, 0);
        #pragma unroll
        for (int j = 0; j < 4; ++j)
            #pragma unroll
            for (int g = 0; g < 2; ++g) {
                o[g][j] = __builtin_amdgcn_mfma_f32_16x16x32_bf16(
                    pf_prev[g][0], vfp[j][0], o[g][j], 0, 0, 0);
                o[g][j] = __builtin_amdgcn_mfma_f32_16x16x32_bf16(
                    pf_prev[g][1], vfp[j][1], o[g][j], 0, 0, 0);
            }
    }

    #pragma unroll
    for (int g = 0; g < 2; ++g) {
        float inv[4];
        #pragma unroll
        for (int r = 0; r < 4; ++r)
            inv[r] = (accl[g][r] > 0.f) ? 1.f / accl[g][r] : 0.f;
        #pragma unroll
        for (int j = 0; j < 4; ++j)
            #pragma unroll
            for (int r = 0; r < 4; ++r) {
                int row = q0 + w * 32 + g * 16 + quad * 4 + r;
                int col = h * HDIM + j * 16 + l15;
                ctx[(size_t)(b * SEQ + row) * D_MODEL + col] =
                    (bf16)(o[g][j][r] * inv[r]);
            }
    }
    #undef STAGE_KV
}

// ---------------------------------------------------------------------------
extern "C" void kernel_launch(void* const* d_in, const int* in_sizes, int n_in,
                              void* d_out, int out_size, void* d_ws, size_t ws_size,
                              hipStream_t stream)
{
    // ws: [0,16K) mbias fp32 | [64K,+32MB) converted bf16 (q,k,v,Wq,Wk,Wv,Wo)
    //     | qproj 8MB | kproj 8MB | vt 8MB | ctx 8MB.   Total ~64.1MB.
    char* wsb = (char*)d_ws;
    float* mbias = (float*)wsb;
    bf16* cbase = (bf16*)(wsb + 65536);
    bf16 *cq = cbase, *ck = cq + ACT_N, *cv = ck + ACT_N;
    bf16 *cWq = cv + ACT_N, *cWk = cWq + W_N, *cWv = cWk + W_N, *cWo = cWv + W_N;
    bf16* qproj = cWo + W_N;
    bf16* kproj = qproj + ACT_N;
    bf16* vt    = kproj + ACT_N;
    bf16* ctx   = vt + ACT_N;
    float* out  = (float*)d_out;

    // allow big dynamic LDS on the 8-wave GEMMs (host-side, capture-safe)
    static bool attrset = false;
    if (!attrset) {
        hipFuncSetAttribute((const void*)k_gemm_proj,
                            hipFuncAttributeMaxDynamicSharedMemorySize, 131072);
        hipFuncSetAttribute((const void*)k_gemm_o,
                            hipFuncAttributeMaxDynamicSharedMemorySize, 131072);
        attrset = true;
    }

    k_convert_all<<<8193, 256, 0, stream>>>(
        (const float*)d_in[0], (const float*)d_in[1], (const float*)d_in[2],
        (const float*)d_in[4], (const float*)d_in[6], (const float*)d_in[8],
        (const float*)d_in[10], cbase, (const unsigned*)d_in[3], mbias);

    k_gemm_proj<<<192, 512, 131072, stream>>>(cq, ck, cv, cWq, cWk, cWv,
                                              (const float*)d_in[5],
                                              (const float*)d_in[7],
                                              (const float*)d_in[9],
                                              qproj, kproj, vt);
    k_attn<<<dim3(64, 8), 256, 0, stream>>>(qproj, kproj, vt, mbias, ctx);
    k_gemm_o<<<128, 512, 98304, stream>>>(ctx, cWo, (const float*)d_in[11], out);
}

// Round 13
// 207.143 us; speedup vs baseline: 1.0612x; 1.0364x over previous
//
#include <hip/hip_runtime.h>
#include <hip/hip_bf16.h>

// B=4, L=S=1024, D=1024, H=16, HD=64. History: R16 256^2/BK=64 8-wave GEMMs
// (proj 192 blk, o-proj 128 blk). R19 (best, 210.2us): attn QBLK=128
// swapped QK^T (S^T=mfma(K,Q)) + T2-involution P both sides + b64 P-store +
// Q in regs. Failed since: R20 V-NT=128 regrid 217 ✗; R21 QBLK=64 2xTLP
// 220 ✗; R22 T15 double-pipeline 215 ✗ (VGPR/LDS/chain costs > overlap).
// Lesson x4: work-per-barrier dominates; QBLK=128@2blk/CU is the local
// optimum. R23 = exact R19 + T5 s_setprio(1) around attn MFMA clusters
// only (m191: +4-7% attn in barrier-free-between-tiles regime; NOT applied
// to lockstep GEMMs per m190).

typedef __bf16 bf16;
typedef __bf16 bf16x4 __attribute__((ext_vector_type(4)));
typedef __bf16 bf16x8 __attribute__((ext_vector_type(8)));
typedef float floatx4 __attribute__((ext_vector_type(4)));

#define D_MODEL 1024
#define NHEAD   16
#define HDIM    64
#define BATCH   4
#define SEQ     1024
#define M_ROWS  (BATCH * SEQ)         // 4096
#define ACT_N   ((size_t)M_ROWS * D_MODEL)    // 4M
#define W_N     ((size_t)D_MODEL * D_MODEL)   // 1M
#define SC2     0.18033688011112042f  // 0.125 * log2(e)

#define GLD(gp, lp) __builtin_amdgcn_global_load_lds( \
    (__attribute__((address_space(1))) void*)(gp), \
    (__attribute__((address_space(3))) void*)(lp), 16, 0, 0)

// ---------------------------------------------------------------------------
// Fused convert + mask (R10-verbatim, verified).
// ---------------------------------------------------------------------------
__global__ __launch_bounds__(256)
void k_convert_all(const float* __restrict__ a0, const float* __restrict__ a1,
                   const float* __restrict__ a2,
                   const float* __restrict__ w0, const float* __restrict__ w1,
                   const float* __restrict__ w2, const float* __restrict__ w3,
                   bf16* __restrict__ dst,
                   const unsigned* __restrict__ m, float* __restrict__ mbias)
{
    if (blockIdx.x == 8192) {
        __shared__ unsigned viol[4];
        __shared__ int fmsh;
        if (threadIdx.x < 4) viol[threadIdx.x] = 0;
        __syncthreads();
        unsigned a = 0, b = 0, c = 0, d = 0;
        for (int i = threadIdx.x; i < 1024; i += 256) {
            unsigned v = m[i];
            if (v > 1u) a = 1;
            if (((v & 0xFFu) > 1u) || (((v >> 8) & 0xFFu) > 1u) ||
                (((v >> 16) & 0xFFu) > 1u) || (((v >> 24) & 0xFFu) > 1u)) b = 1;
            unsigned lo = v & 0xFFFFu, hi = v >> 16;
            if (!((lo == 0u || lo == 0x3F80u) && (hi == 0u || hi == 0x3F80u))) c = 1;
            if (lo != 0u) d = 1;
        }
        if (a) atomicOr(&viol[0], 1u);
        if (b) atomicOr(&viol[1], 1u);
        if (c) atomicOr(&viol[2], 1u);
        if (d) atomicOr(&viol[3], 1u);
        __syncthreads();
        if (threadIdx.x == 0) {
            int fm;
            if (!viol[0])      fm = 1;
            else if (!viol[1]) fm = 0;
            else if (!viol[2]) fm = viol[3] ? 2 : 3;
            else               fm = 0;
            fmsh = fm;
        }
        __syncthreads();
        const int fm = fmsh;
        for (int i = 0; i < 16; ++i) {
            int s = i * 256 + threadIdx.x;
            bool msk;
            if (fm == 1)      msk = ((const int*)m)[s] != 0;
            else if (fm == 2) msk = ((const unsigned short*)m)[s] != 0;
            else if (fm == 3) msk = ((const unsigned*)m)[s] != 0;
            else              msk = ((const unsigned char*)m)[s] != 0;
            mbias[s] = msk ? -1e30f : 0.f;
        }
        return;
    }

    size_t i = ((size_t)blockIdx.x * 256 + threadIdx.x) * 8;
    const float* src; size_t off;
    if (i < ((size_t)12 << 20)) {
        int z = (int)(i >> 22);
        src = (z == 0) ? a0 : (z == 1) ? a1 : a2;
        off = i & (((size_t)1 << 22) - 1);
    } else {
        size_t r = i - ((size_t)12 << 20);
        int j = (int)(r >> 20);
        src = (j == 0) ? w0 : (j == 1) ? w1 : (j == 2) ? w2 : w3;
        off = r & (((size_t)1 << 20) - 1);
    }
    float4 f0 = ((const float4*)(src + off))[0];
    float4 f1 = ((const float4*)(src + off))[1];
    bf16x8 o;
    o[0] = (bf16)f0.x; o[1] = (bf16)f0.y; o[2] = (bf16)f0.z; o[3] = (bf16)f0.w;
    o[4] = (bf16)f1.x; o[5] = (bf16)f1.y; o[6] = (bf16)f1.z; o[7] = (bf16)f1.w;
    *(bf16x8*)(dst + i) = o;
}

// ---------------------------------------------------------------------------
// 256xNT / BK=64 / 8-wave GEMM core (R16-verified at NT=256, R17 at NT=128).
// ---------------------------------------------------------------------------
template<typename CT, int NT>
__device__ __forceinline__ void gemm8_core(const bf16* __restrict__ A,
                                           const bf16* __restrict__ W,
                                           const float* __restrict__ bias,
                                           CT* __restrict__ C,
                                           int m0, int n0, bool rowBias,
                                           bf16* __restrict__ As0,
                                           bf16* __restrict__ Bs0)
{
    const int t    = threadIdx.x;     // 0..511
    const int lane = t & 63;
    const int w    = t >> 6;          // 0..7
    const int wm   = w >> 2;          // 0..1
    const int wn   = w & 3;           // 0..3
    const int l15  = lane & 15;
    const int quad = lane >> 4;
    const int lx   = l15 & 7;

    constexpr int NJ = NT / 128;      // B jj-count per quadrant (2 or 1)
    constexpr int BSTRIDE = NT * 64;  // elems per B buffer

    floatx4 acc[8][NT / 64] = {};

    int srow[2], schk[2], ldso[2];
    #pragma unroll
    for (int j = 0; j < 2; ++j) {
        int i = j * 512 + t;
        srow[j] = i >> 3;
        schk[j] = (i & 7) ^ (srow[j] & 7);
        ldso[j] = (j * 512 + w * 64) * 8;
    }

    #define STAGE_HALF(src, rb, k0s, h, dstbuf) do {                          \
        _Pragma("unroll")                                                     \
        for (int j = 0; j < 2; ++j)                                           \
            GLD((src) + (size_t)((rb) + (h) * 128 + srow[j]) * D_MODEL        \
                    + (k0s) + schk[j] * 8,                                    \
                (dstbuf) + (h) * 8192 + ldso[j]);                             \
    } while (0)

    // prologue: tile 0 -> buffer 0
    STAGE_HALF(A, m0, 0, 0, As0);
    STAGE_HALF(A, m0, 0, 1, As0);
    STAGE_HALF(W, n0, 0, 0, Bs0);
    if constexpr (NT == 256) STAGE_HALF(W, n0, 0, 1, Bs0);
    __syncthreads();

    for (int kt = 0; kt < 16; ++kt) {
        const int nk = (kt + 1) * 64;
        const bf16* __restrict__ Ab = As0 + (kt & 1) * 16384;
        const bf16* __restrict__ Bb = Bs0 + (kt & 1) * BSTRIDE;
        bf16* __restrict__ An = As0 + ((kt + 1) & 1) * 16384;
        bf16* __restrict__ Bn = Bs0 + ((kt + 1) & 1) * BSTRIDE;

        #pragma unroll
        for (int ph = 0; ph < 4; ++ph) {
            const int mq = ph >> 1, nq = ph & 1;

            if (nk < D_MODEL) {       // stage one half of tile kt+1
                if constexpr (NT == 256) {
                    if (ph == 0)      STAGE_HALF(A, m0, nk, 0, An);
                    else if (ph == 1) STAGE_HALF(A, m0, nk, 1, An);
                    else if (ph == 2) STAGE_HALF(W, n0, nk, 0, Bn);
                    else              STAGE_HALF(W, n0, nk, 1, Bn);
                } else {
                    if (ph == 0)      STAGE_HALF(A, m0, nk, 0, An);
                    else if (ph == 1) STAGE_HALF(A, m0, nk, 1, An);
                    else if (ph == 2) STAGE_HALF(W, n0, nk, 0, Bn);
                }
            }

            bf16x8 af[4][2], bfr[NJ][2];
            #pragma unroll
            for (int ii = 0; ii < 4; ++ii) {
                int row = wm * 128 + mq * 64 + ii * 16 + l15;
                #pragma unroll
                for (int kk = 0; kk < 2; ++kk)
                    af[ii][kk] = *(const bf16x8*)
                        &Ab[row * 64 + (((kk * 4 + quad) ^ lx)) * 8];
            }
            #pragma unroll
            for (int jj = 0; jj < NJ; ++jj) {
                int row = wn * (NT / 4) + nq * (NT / 8) + jj * 16 + l15;
                #pragma unroll
                for (int kk = 0; kk < 2; ++kk)
                    bfr[jj][kk] = *(const bf16x8*)
                        &Bb[row * 64 + (((kk * 4 + quad) ^ lx)) * 8];
            }

            #pragma unroll
            for (int ii = 0; ii < 4; ++ii)
                #pragma unroll
                for (int jj = 0; jj < NJ; ++jj)
                    #pragma unroll
                    for (int kk = 0; kk < 2; ++kk)
                        acc[mq * 4 + ii][nq * NJ + jj] =
                            __builtin_amdgcn_mfma_f32_16x16x32_bf16(
                                af[ii][kk], bfr[jj][kk],
                                acc[mq * 4 + ii][nq * NJ + jj], 0, 0, 0);
        }
        __syncthreads();
    }

    // epilogue: C/D layout col=lane&15, row=quad*4+r
    #pragma unroll
    for (int i = 0; i < 8; ++i) {
        int rowb = m0 + wm * 128 + i * 16 + quad * 4;
        float bvr[4];
        if (rowBias) {
            #pragma unroll
            for (int r = 0; r < 4; ++r) bvr[r] = bias[rowb + r];
        }
        #pragma unroll
        for (int jf = 0; jf < NT / 64; ++jf) {
            int col = n0 + wn * (NT / 4) + jf * 16 + l15;
            float bc = rowBias ? 0.f : bias[col];
            #pragma unroll
            for (int r = 0; r < 4; ++r) {
                float val = acc[i][jf][r] + (rowBias ? bvr[r] : bc);
                C[(size_t)(rowb + r) * D_MODEL + col] = (CT)val;
            }
        }
    }
    #undef STAGE_HALF
}

// ---------------------------------------------------------------------------
// Fused projection GEMM (R19-verified): 192 blocks x 512 thr, XCD-chunked.
// ---------------------------------------------------------------------------
__global__ __launch_bounds__(512, 2)
void k_gemm_proj(const bf16* __restrict__ cq, const bf16* __restrict__ ck,
                 const bf16* __restrict__ cv,
                 const bf16* __restrict__ cWq, const bf16* __restrict__ cWk,
                 const bf16* __restrict__ cWv,
                 const float* __restrict__ bq, const float* __restrict__ bk,
                 const float* __restrict__ bv,
                 bf16* __restrict__ qproj, bf16* __restrict__ kproj,
                 bf16* __restrict__ vt)
{
    extern __shared__ __align__(16) bf16 smem[];
    bf16* As0 = smem;            // 2 x 16384 elems
    bf16* Bs0 = smem + 32768;    // 2 x 16384 elems

    const int bid = blockIdx.x;
    const int tid = (bid & 7) * 24 + (bid >> 3);   // 0..191
    if (tid < 64) {
        gemm8_core<bf16, 256>(cq, cWq, bq, qproj,
                              (tid >> 2) * 256, (tid & 3) * 256, false, As0, Bs0);
    } else if (tid < 128) {
        int u = tid - 64;
        gemm8_core<bf16, 256>(ck, cWk, bk, kproj,
                              (u >> 2) * 256, (u & 3) * 256, false, As0, Bs0);
    } else {
        int v = tid - 128;
        int b = v >> 4, m = (v >> 2) & 3, n = v & 3;
        gemm8_core<bf16, 256>(cWv, cv + (size_t)b * W_N, bv,
                              vt + (size_t)b * W_N, m * 256, n * 256, true,
                              As0, Bs0);
    }
}

// O-projection: 128 blocks x 512 thr, 256x128 tiles (16 m x 8 n), XCD-chunked.
__global__ __launch_bounds__(512, 2)
void k_gemm_o(const bf16* __restrict__ A, const bf16* __restrict__ W,
              const float* __restrict__ bb, float* __restrict__ C)
{
    extern __shared__ __align__(16) bf16 smem[];
    bf16* As0 = smem;            // 2 x 16384 elems
    bf16* Bs0 = smem + 32768;    // 2 x 8192 elems

    const int bid = blockIdx.x;
    const int tid = (bid & 7) * 16 + (bid >> 3);   // 0..127
    gemm8_core<float, 128>(A, W, bb, C, (tid >> 3) * 256, (tid & 7) * 128,
                           false, As0, Bs0);
}

// ---------------------------------------------------------------------------
// Flash attention, QBLK=128, swapped QK^T (R19-verified) + T5 setprio (R23).
// Grid (64, 8), 256 thr (4 waves); wave owns 32 q = 2 groups g of 16.
// Q in regs. S^T = mfma(K, Q); P-store = 8 aligned ds_write_b64 with T2
// involution c^=((c>>3)&7) on both sides. setprio(1) wraps the QK^T and
// accl/PV MFMA clusters — waves within a block are barrier-free between
// tile boundaries, so the CU scheduler can favor the MFMA-phase wave (m191).
// LDS 48KB.
// ---------------------------------------------------------------------------
__global__ __launch_bounds__(256)
void k_attn(const bf16* __restrict__ qproj, const bf16* __restrict__ kproj,
            const bf16* __restrict__ vt, const float* __restrict__ mbias_g,
            bf16* __restrict__ ctx)
{
    __shared__ alignas(16) bf16 Kst[2][4096];  // [f=j*2+kk][lane]*8, frag order
    __shared__ alignas(16) bf16 Vst[2][4096];
    __shared__ alignas(16) bf16 Past[8192];    // per-wave 2048, swizzled

    const int t    = threadIdx.x;
    const int lane = t & 63;
    const int w    = t >> 6;
    const int l15  = lane & 15;
    const int quad = lane >> 4;

    const int b  = blockIdx.x >> 4;
    const int h  = blockIdx.x & 15;
    const int q0 = blockIdx.y * 128;

    // stage K/V tile 0 into buffer 0
    #pragma unroll
    for (int i = 0; i < 2; ++i) {
        int f   = w * 2 + i;
        int row = (f >> 1) * 16 + l15;          // s-row (K) / d-row (Vt)
        int cb  = (f & 1) * 32 + quad * 8;
        GLD(kproj + (size_t)(b * SEQ + row) * D_MODEL + h * HDIM + cb,
            Kst[0] + f * 512);
        GLD(vt + (size_t)(b * 1024 + h * HDIM + row) * D_MODEL + cb,
            Vst[0] + f * 512);
    }

    // Q fragments: direct per-lane 16B global loads (B-operand layout)
    bf16x8 qf[2][2];
    #pragma unroll
    for (int g = 0; g < 2; ++g)
        #pragma unroll
        for (int kk = 0; kk < 2; ++kk)
            qf[g][kk] = *(const bf16x8*)(qproj
                + (size_t)(b * SEQ + q0 + w * 32 + g * 16 + l15) * D_MODEL
                + h * HDIM + kk * 32 + quad * 8);

    __syncthreads();

    bf16x8 ones;
    #pragma unroll
    for (int e = 0; e < 8; ++e) ones[e] = (bf16)1.0f;

    floatx4 o[2][4] = {};
    floatx4 accl[2] = {};

    const int rswz = lane ^ ((lane >> 3) & 7);   // read-side swizzled chunk
    const float* __restrict__ mbb = mbias_g + b * SEQ;

    int cur = 0;
    for (int s0 = 0; s0 < SEQ; s0 += 64) {
        // prefetch next K/V tile into the other buffer BEFORE compute
        if (s0 + 64 < SEQ) {
            #pragma unroll
            for (int i = 0; i < 2; ++i) {
                int f   = w * 2 + i;
                int row = (f >> 1) * 16 + l15;
                int cb  = (f & 1) * 32 + quad * 8;
                GLD(kproj + (size_t)(b * SEQ + s0 + 64 + row) * D_MODEL
                        + h * HDIM + cb,
                    Kst[cur ^ 1] + f * 512);
                GLD(vt + (size_t)(b * 1024 + h * HDIM + row) * D_MODEL
                        + s0 + 64 + cb,
                    Vst[cur ^ 1] + f * 512);
            }
        }

        // swapped QK^T: S^T[s][q] = mfma(A=K, B=Q)
        floatx4 s_acc[2][4] = {};
        __builtin_amdgcn_s_setprio(1);
        #pragma unroll
        for (int j = 0; j < 4; ++j) {
            bf16x8 kf0 = *(const bf16x8*)&Kst[cur][(j * 2 + 0) * 512 + lane * 8];
            bf16x8 kf1 = *(const bf16x8*)&Kst[cur][(j * 2 + 1) * 512 + lane * 8];
            #pragma unroll
            for (int g = 0; g < 2; ++g) {
                s_acc[g][j] = __builtin_amdgcn_mfma_f32_16x16x32_bf16(
                    kf0, qf[g][0], s_acc[g][j], 0, 0, 0);
                s_acc[g][j] = __builtin_amdgcn_mfma_f32_16x16x32_bf16(
                    kf1, qf[g][1], s_acc[g][j], 0, 0, 0);
            }
        }
        __builtin_amdgcn_s_setprio(0);

        // softmax numerator -> packed b64 P store (4 consecutive s per write)
        #pragma unroll
        for (int j = 0; j < 4; ++j) {
            float4 mb4 = *(const float4*)&mbb[s0 + j * 16 + quad * 4];
            int c = (j >> 1) * 64 + ((j & 1) * 2 + (quad >> 1)) * 16 + l15;
            int phys = c ^ ((c >> 3) & 7);
            #pragma unroll
            for (int g = 0; g < 2; ++g) {
                bf16x4 pk;
                pk[0] = (bf16)__builtin_amdgcn_exp2f(
                    fmaf(s_acc[g][j][0], SC2, mb4.x));
                pk[1] = (bf16)__builtin_amdgcn_exp2f(
                    fmaf(s_acc[g][j][1], SC2, mb4.y));
                pk[2] = (bf16)__builtin_amdgcn_exp2f(
                    fmaf(s_acc[g][j][2], SC2, mb4.z));
                pk[3] = (bf16)__builtin_amdgcn_exp2f(
                    fmaf(s_acc[g][j][3], SC2, mb4.w));
                *(bf16x4*)&Past[(w * 2 + g) * 1024 + phys * 8
                                + (quad & 1) * 4] = pk;
            }
        }
        __builtin_amdgcn_wave_barrier();

        bf16x8 pf[2][2];
        #pragma unroll
        for (int g = 0; g < 2; ++g)
            #pragma unroll
            for (int kk = 0; kk < 2; ++kk)
                pf[g][kk] = *(const bf16x8*)
                    &Past[(w * 2 + g) * 1024 + (kk * 64 + rswz) * 8];

        __builtin_amdgcn_s_setprio(1);
        #pragma unroll
        for (int g = 0; g < 2; ++g)
            #pragma unroll
            for (int kk = 0; kk < 2; ++kk)
                accl[g] = __builtin_amdgcn_mfma_f32_16x16x32_bf16(
                    pf[g][kk], ones, accl[g], 0, 0, 0);

        #pragma unroll
        for (int j = 0; j < 4; ++j) {
            bf16x8 vf0 = *(const bf16x8*)&Vst[cur][(j * 2 + 0) * 512 + lane * 8];
            bf16x8 vf1 = *(const bf16x8*)&Vst[cur][(j * 2 + 1) * 512 + lane * 8];
            #pragma unroll
            for (int g = 0; g < 2; ++g) {
                o[g][j] = __builtin_amdgcn_mfma_f32_16x16x32_bf16(
                    pf[g][0], vf0, o[g][j], 0, 0, 0);
                o[g][j] = __builtin_amdgcn_mfma_f32_16x16x32_bf16(
                    pf[g][1], vf1, o[g][j], 0, 0, 0);
            }
        }
        __builtin_amdgcn_s_setprio(0);

        __syncthreads();   // next K/V tile landed; buffers swap
        cur ^= 1;
    }

    #pragma unroll
    for (int g = 0; g < 2; ++g) {
        float inv[4];
        #pragma unroll
        for (int r = 0; r < 4; ++r)
            inv[r] = (accl[g][r] > 0.f) ? 1.f / accl[g][r] : 0.f;
        #pragma unroll
        for (int j = 0; j < 4; ++j)
            #pragma unroll
            for (int r = 0; r < 4; ++r) {
                int row = q0 + w * 32 + g * 16 + quad * 4 + r;
                int col = h * HDIM + j * 16 + l15;
                ctx[(size_t)(b * SEQ + row) * D_MODEL + col] =
                    (bf16)(o[g][j][r] * inv[r]);
            }
    }
}

// ---------------------------------------------------------------------------
extern "C" void kernel_launch(void* const* d_in, const int* in_sizes, int n_in,
                              void* d_out, int out_size, void* d_ws, size_t ws_size,
                              hipStream_t stream)
{
    // ws: [0,16K) mbias fp32 | [64K,+32MB) converted bf16 (q,k,v,Wq,Wk,Wv,Wo)
    //     | qproj 8MB | kproj 8MB | vt 8MB | ctx 8MB.   Total ~64.1MB.
    char* wsb = (char*)d_ws;
    float* mbias = (float*)wsb;
    bf16* cbase = (bf16*)(wsb + 65536);
    bf16 *cq = cbase, *ck = cq + ACT_N, *cv = ck + ACT_N;
    bf16 *cWq = cv + ACT_N, *cWk = cWq + W_N, *cWv = cWk + W_N, *cWo = cWv + W_N;
    bf16* qproj = cWo + W_N;
    bf16* kproj = qproj + ACT_N;
    bf16* vt    = kproj + ACT_N;
    bf16* ctx   = vt + ACT_N;
    float* out  = (float*)d_out;

    // allow big dynamic LDS on the 8-wave GEMMs (host-side, capture-safe)
    static bool attrset = false;
    if (!attrset) {
        hipFuncSetAttribute((const void*)k_gemm_proj,
                            hipFuncAttributeMaxDynamicSharedMemorySize, 131072);
        hipFuncSetAttribute((const void*)k_gemm_o,
                            hipFuncAttributeMaxDynamicSharedMemorySize, 131072);
        attrset = true;
    }

    k_convert_all<<<8193, 256, 0, stream>>>(
        (const float*)d_in[0], (const float*)d_in[1], (const float*)d_in[2],
        (const float*)d_in[4], (const float*)d_in[6], (const float*)d_in[8],
        (const float*)d_in[10], cbase, (const unsigned*)d_in[3], mbias);

    k_gemm_proj<<<192, 512, 131072, stream>>>(cq, ck, cv, cWq, cWk, cWv,
                                              (const float*)d_in[5],
                                              (const float*)d_in[7],
                                              (const float*)d_in[9],
                                              qproj, kproj, vt);
    k_attn<<<dim3(64, 8), 256, 0, stream>>>(qproj, kproj, vt, mbias, ctx);
    k_gemm_o<<<128, 512, 98304, stream>>>(ctx, cWo, (const float*)d_in[11], out);
}